// Round 2
// baseline (937.034 us; speedup 1.0000x reference)
//
#include <hip/hip_runtime.h>
#include <stdint.h>

__device__ __forceinline__ float bf2f(uint32_t v) { return __uint_as_float(v << 16); }
__device__ __forceinline__ uint32_t f2bf(float f) {
  uint32_t u = __float_as_uint(f);
  return (u + 0x7fffu + ((u >> 16) & 1u)) >> 16;  // RNE
}

// ---------------------------------------------------------------------------
// Kernel A: two-level Haar DWT.
// x (32,128,128,128) f32 -> bands bf16, layout [k][pos=h*32+w][b][i]
// Each level-2 band value = 0.25 * signed sum of the four 2x2-block sums of a
// 4x4 block of x. Block = (b, h, 16-channel group); LDS transpose so the
// [b][i]-contiguous band layout is written coalesced.
// ---------------------------------------------------------------------------
__global__ __launch_bounds__(256) void dwt_kernel(const float* __restrict__ x,
                                                  uint16_t* __restrict__ bands) {
  __shared__ uint16_t tile[4][32][16];
  const int bid = blockIdx.x;
  const int cg = bid & 7;          // channel group (16 ch)
  const int h  = (bid >> 3) & 31;  // output row
  const int b  = bid >> 8;         // batch
  const int t  = threadIdx.x;
  const int w  = t & 31;           // output col
  const int cl = t >> 5;           // 0..7
#pragma unroll
  for (int cc = 0; cc < 2; ++cc) {
    const int c = cl + (cc << 3);  // 0..15 within group
    const float* xc = x + (((size_t)(b << 7) + (cg << 4) + c) << 14) + (h << 9) + (w << 2);
    float4 r0 = *(const float4*)(xc);
    float4 r1 = *(const float4*)(xc + 128);
    float4 r2 = *(const float4*)(xc + 256);
    float4 r3 = *(const float4*)(xc + 384);
    float S00 = r0.x + r0.y + r1.x + r1.y;
    float S01 = r0.z + r0.w + r1.z + r1.w;
    float S10 = r2.x + r2.y + r3.x + r3.y;
    float S11 = r2.z + r2.w + r3.z + r3.w;
    tile[0][w][c] = (uint16_t)f2bf(0.25f * (S00 + S01 + S10 + S11));  // ll
    tile[1][w][c] = (uint16_t)f2bf(0.25f * (S00 - S01 + S10 - S11));  // lh
    tile[2][w][c] = (uint16_t)f2bf(0.25f * (S00 + S01 - S10 - S11));  // hl
    tile[3][w][c] = (uint16_t)f2bf(0.25f * (S00 - S01 - S10 + S11));  // hh
  }
  __syncthreads();
  const uint32_t* tl = (const uint32_t*)&tile[0][0][0];
  uint32_t* bo = (uint32_t*)bands;
#pragma unroll
  for (int j = 0; j < 4; ++j) {
    const int idx = t + (j << 8);      // 1024 uints = 2048 bf16 (4*32*16)
    const int k   = idx >> 8;
    const int rem = idx & 255;
    const int w2  = rem >> 3;
    const int qq  = rem & 7;
    // bands uint index: (k*1024 + h*32 + w2)*2048 + b*64 + cg*8 + qq
    bo[((size_t)((k << 10) + (h << 5) + w2) << 11) + (b << 6) + (cg << 3) + qq] = tl[idx];
  }
}

// ---------------------------------------------------------------------------
// Kernel B: transpose weights (i,o,16,16) f32 -> Wt bf16 [k][yx][i*128+o]
// so kernel C can load per-gridpoint 128x128 slices coalesced.
// ---------------------------------------------------------------------------
__global__ __launch_bounds__(256) void wprep_kernel(const float* __restrict__ w1,
                                                    const float* __restrict__ w2,
                                                    const float* __restrict__ w3,
                                                    const float* __restrict__ w4,
                                                    uint16_t* __restrict__ Wt) {
  const int bid = blockIdx.x;        // 256 blocks: k = bid>>6, 4 yx per block
  const int k  = bid >> 6;
  const int y4 = (bid & 63) << 2;    // yx base
  const float* src = (k == 0) ? w1 : (k == 1) ? w2 : (k == 2) ? w3 : w4;
  const int t = threadIdx.x;
  for (int j = 0; j < 64; ++j) {
    const int io = t + (j << 8);
    float4 v = *(const float4*)(src + ((size_t)io << 8) + y4);
    Wt[((size_t)((k << 8) + y4 + 0) << 14) + io] = (uint16_t)f2bf(v.x);
    Wt[((size_t)((k << 8) + y4 + 1) << 14) + io] = (uint16_t)f2bf(v.y);
    Wt[((size_t)((k << 8) + y4 + 2) << 14) + io] = (uint16_t)f2bf(v.z);
    Wt[((size_t)((k << 8) + y4 + 3) << 14) + io] = (uint16_t)f2bf(v.w);
  }
}

// jax.image.resize bilinear 16->32 closed form (edge renorm == clamp)
__device__ __forceinline__ void interp_coord(int p, int& i0, int& i1, float& f) {
  if (p == 0)       { i0 = 0;  i1 = 0;  f = 0.f; }
  else if (p == 31) { i0 = 15; i1 = 15; f = 0.f; }
  else if (p & 1)   { i0 = (p - 1) >> 1; i1 = i0 + 1; f = 0.25f; }
  else              { i0 = (p >> 1) - 1; i1 = i0 + 1; f = 0.75f; }
}

// ---------------------------------------------------------------------------
// Kernel C: one block per spatial position (h,w). For each band: build the
// bilinear-interpolated 128x128 W slice in LDS (bf16), stage A^T (i-major,
// fp32) in LDS, run the 32x128x128 fp32 GEMM (4x4 per thread), accumulate the
// four IDWT sign combos, then write the fused idwt+2x-upsample 4x4 output
// block per (b,o).
// ---------------------------------------------------------------------------
__global__ __launch_bounds__(256) void gemm_kernel(const uint16_t* __restrict__ bands,
                                                   const uint16_t* __restrict__ Wt,
                                                   float* __restrict__ out) {
  __shared__ uint16_t Ws[128 * 128];   // 32 KB, bf16 W slice, [i][o]
  __shared__ float At[128 * 36];       // 18 KB, fp32 A^T, [i][b], row pad 36
  const int p = blockIdx.x;
  const int h = p >> 5, w = p & 31;
  int y0, y1, x0, x1; float fy, fx;
  interp_coord(h, y0, y1, fy);
  interp_coord(w, x0, x1, fx);
  const float c00 = (1.f - fy) * (1.f - fx), c01 = (1.f - fy) * fx;
  const float c10 = fy * (1.f - fx),         c11 = fy * fx;
  const int t = threadIdx.x;
  const int g = t & 7;    // b-group: b = 4g+db
  const int q = t >> 3;   // o-group: o = 4q+dq
  float v00[16], v01[16], v10[16], v11[16];
#pragma unroll
  for (int j = 0; j < 16; ++j) { v00[j] = 0.f; v01[j] = 0.f; v10[j] = 0.f; v11[j] = 0.f; }

  for (int k = 0; k < 4; ++k) {
    __syncthreads();  // protect previous iteration's LDS reads
    const uint16_t* p00 = Wt + ((size_t)((k << 8) + (y0 << 4) + x0) << 14);
    const uint16_t* p01 = Wt + ((size_t)((k << 8) + (y0 << 4) + x1) << 14);
    const uint16_t* p10 = Wt + ((size_t)((k << 8) + (y1 << 4) + x0) << 14);
    const uint16_t* p11 = Wt + ((size_t)((k << 8) + (y1 << 4) + x1) << 14);
    uint32_t* Wsu = (uint32_t*)Ws;
#pragma unroll
    for (int j = 0; j < 8; ++j) {
      const int e = (t + (j << 8)) << 3;  // 8 bf16 per thread-iter
      const uint4 u0 = *(const uint4*)(p00 + e);
      const uint4 u1 = *(const uint4*)(p01 + e);
      const uint4 u2 = *(const uint4*)(p10 + e);
      const uint4 u3 = *(const uint4*)(p11 + e);
      const uint32_t* a0 = (const uint32_t*)&u0;
      const uint32_t* a1 = (const uint32_t*)&u1;
      const uint32_t* a2 = (const uint32_t*)&u2;
      const uint32_t* a3 = (const uint32_t*)&u3;
#pragma unroll
      for (int m = 0; m < 4; ++m) {
        float lo = c00 * bf2f(a0[m] & 0xffffu) + c01 * bf2f(a1[m] & 0xffffu)
                 + c10 * bf2f(a2[m] & 0xffffu) + c11 * bf2f(a3[m] & 0xffffu);
        float hi = c00 * bf2f(a0[m] >> 16) + c01 * bf2f(a1[m] >> 16)
                 + c10 * bf2f(a2[m] >> 16) + c11 * bf2f(a3[m] >> 16);
        Wsu[(e >> 1) + m] = f2bf(lo) | (f2bf(hi) << 16);
      }
    }
    // stage A^T: bands[k][p][b][i] bf16 -> At[i][b] fp32
    const uint32_t* ab = (const uint32_t*)(bands + ((size_t)((k << 10) + p) << 12));
#pragma unroll
    for (int j = 0; j < 8; ++j) {
      const int idx = t + (j << 8);        // 2048 uints = 4096 bf16
      const uint32_t u = ab[idx];
      const int bb = idx >> 6;
      const int i0 = (idx & 63) << 1;
      At[i0 * 36 + bb]       = bf2f(u & 0xffffu);
      At[(i0 + 1) * 36 + bb] = bf2f(u >> 16);
    }
    __syncthreads();

    float acc[16];
#pragma unroll
    for (int j = 0; j < 16; ++j) acc[j] = 0.f;
    const uint32_t* WsuC = (const uint32_t*)Ws;
#pragma unroll 8
    for (int i = 0; i < 128; ++i) {
      float4 av = *(const float4*)&At[i * 36 + (g << 2)];
      uint2 wu  = *(const uint2*)&WsuC[(i << 6) + (q << 1)];
      float w0_ = bf2f(wu.x & 0xffffu), w1_ = bf2f(wu.x >> 16);
      float w2_ = bf2f(wu.y & 0xffffu), w3_ = bf2f(wu.y >> 16);
      acc[0]  += av.x * w0_; acc[1]  += av.x * w1_; acc[2]  += av.x * w2_; acc[3]  += av.x * w3_;
      acc[4]  += av.y * w0_; acc[5]  += av.y * w1_; acc[6]  += av.y * w2_; acc[7]  += av.y * w3_;
      acc[8]  += av.z * w0_; acc[9]  += av.z * w1_; acc[10] += av.z * w2_; acc[11] += av.z * w3_;
      acc[12] += av.w * w0_; acc[13] += av.w * w1_; acc[14] += av.w * w2_; acc[15] += av.w * w3_;
    }
    // IDWT sign fold: bands order A=ll,B=lh,C=hl,D=hh
    const float sg01 = (k == 1 || k == 3) ? -1.f : 1.f;
    const float sg10 = (k >= 2) ? -1.f : 1.f;
    const float sg11 = (k == 1 || k == 2) ? -1.f : 1.f;
#pragma unroll
    for (int j = 0; j < 16; ++j) {
      const float a = acc[j];
      v00[j] += a;
      v01[j] += sg01 * a;
      v10[j] += sg10 * a;
      v11[j] += sg11 * a;
    }
  }

  // Fused idwt (x0.5) + zero-band upsample (x0.5): 4x4 output block per (b,o)
#pragma unroll
  for (int db = 0; db < 4; ++db) {
    const int bb = (g << 2) + db;
#pragma unroll
    for (int dq = 0; dq < 4; ++dq) {
      const int oo = (q << 2) + dq;
      const int j = (db << 2) + dq;
      const float a00 = 0.25f * v00[j], a01 = 0.25f * v01[j];
      const float a10 = 0.25f * v10[j], a11 = 0.25f * v11[j];
      float* ob = out + (((size_t)(bb << 7) + oo) << 14) + (h << 9) + (w << 2);
      float4 top = make_float4(a00, a00, a01, a01);
      float4 bot = make_float4(a10, a10, a11, a11);
      *(float4*)(ob)       = top;
      *(float4*)(ob + 128) = top;
      *(float4*)(ob + 256) = bot;
      *(float4*)(ob + 384) = bot;
    }
  }
}

extern "C" void kernel_launch(void* const* d_in, const int* in_sizes, int n_in,
                              void* d_out, int out_size, void* d_ws, size_t ws_size,
                              hipStream_t stream) {
  const float* x  = (const float*)d_in[0];
  const float* w1 = (const float*)d_in[1];
  const float* w2 = (const float*)d_in[2];
  const float* w3 = (const float*)d_in[3];
  const float* w4 = (const float*)d_in[4];
  float* out = (float*)d_out;

  uint16_t* bands = (uint16_t*)d_ws;              // 4*1024*4096 bf16 = 33.5 MB
  uint16_t* Wt    = bands + (size_t)16777216;     // 4*256*16384 bf16 = 33.5 MB

  dwt_kernel<<<8192, 256, 0, stream>>>(x, bands);
  wprep_kernel<<<256, 256, 0, stream>>>(w1, w2, w3, w4, Wt);
  gemm_kernel<<<1024, 256, 0, stream>>>(bands, Wt, out);
}

// Round 3
// 653.707 us; speedup vs baseline: 1.4334x; 1.4334x over previous
//
#include <hip/hip_runtime.h>
#include <stdint.h>

__device__ __forceinline__ float bf2f(uint32_t v) { return __uint_as_float(v << 16); }
__device__ __forceinline__ uint32_t f2bf(float f) {
  uint32_t u = __float_as_uint(f);
  return (u + 0x7fffu + ((u >> 16) & 1u)) >> 16;  // RNE
}

// jax.image.resize bilinear 16->32 closed form (edge renorm == clamp)
__device__ __forceinline__ void interp_coord(int p, int& i0, int& i1, float& f) {
  if (p == 0)       { i0 = 0;  i1 = 0;  f = 0.f; }
  else if (p == 31) { i0 = 15; i1 = 15; f = 0.f; }
  else if (p & 1)   { i0 = (p - 1) >> 1; i1 = i0 + 1; f = 0.25f; }
  else              { i0 = (p >> 1) - 1; i1 = i0 + 1; f = 0.75f; }
}

// ---------------------------------------------------------------------------
// Kernel A: two-level Haar DWT.  x (32,128,128,128) f32 -> bands bf16
// layout [k][p=h*32+w][b][i].  Block = (b, h, 32-channel group) so that band
// writes are 64B full-line segments.
// ---------------------------------------------------------------------------
__global__ __launch_bounds__(256) void dwt_kernel(const float* __restrict__ x,
                                                  uint16_t* __restrict__ bands) {
  __shared__ uint16_t tile[4 * 32 * 34];  // [k][w][c pad 34], 8.7 KB
  const int bid = blockIdx.x;
  const int cg4 = bid & 3;          // 32-channel group
  const int h   = (bid >> 2) & 31;  // output row
  const int b   = bid >> 7;         // batch
  const int t   = threadIdx.x;
  const int w   = t & 31;           // output col
  const int cl  = t >> 5;           // 0..7
#pragma unroll
  for (int cc = 0; cc < 4; ++cc) {
    const int c = cl + (cc << 3);   // 0..31 local channel
    const float* xc = x + (((size_t)(b << 7) + (cg4 << 5) + c) << 14) + (h << 9) + (w << 2);
    float4 r0 = *(const float4*)(xc);
    float4 r1 = *(const float4*)(xc + 128);
    float4 r2 = *(const float4*)(xc + 256);
    float4 r3 = *(const float4*)(xc + 384);
    float S00 = r0.x + r0.y + r1.x + r1.y;
    float S01 = r0.z + r0.w + r1.z + r1.w;
    float S10 = r2.x + r2.y + r3.x + r3.y;
    float S11 = r2.z + r2.w + r3.z + r3.w;
    tile[(0 * 32 + w) * 34 + c] = (uint16_t)f2bf(0.25f * (S00 + S01 + S10 + S11));  // ll
    tile[(1 * 32 + w) * 34 + c] = (uint16_t)f2bf(0.25f * (S00 - S01 + S10 - S11));  // lh
    tile[(2 * 32 + w) * 34 + c] = (uint16_t)f2bf(0.25f * (S00 + S01 - S10 - S11));  // hl
    tile[(3 * 32 + w) * 34 + c] = (uint16_t)f2bf(0.25f * (S00 - S01 - S10 + S11));  // hh
  }
  __syncthreads();
  const uint32_t* tl = (const uint32_t*)tile;
  uint32_t* bo = (uint32_t*)bands;
#pragma unroll
  for (int j = 0; j < 8; ++j) {
    const int idx = t + (j << 8);   // 0..2047
    const int k   = idx >> 9;
    const int rem = idx & 511;
    const int w2  = rem >> 4;
    const int qq  = rem & 15;       // i-pair within 32-ch group
    const uint32_t v = tl[(k * 32 + w2) * 17 + qq];
    bo[(((size_t)(k << 10) + (h << 5) + w2) << 11) + (b << 6) + (cg4 << 4) + qq] = v;
  }
}

// ---------------------------------------------------------------------------
// Kernel B: build fully-interpolated W32[k][p][io] bf16 (134 MB, in d_out).
// Block = (k, 64-io chunk); stage w[io0..+64][256 yx] in LDS, then emit all
// 1024 positions' bilinear values for those 64 io, coalesced both sides.
// ---------------------------------------------------------------------------
__global__ __launch_bounds__(256) void winterp_kernel(const float* __restrict__ w1,
                                                      const float* __restrict__ w2,
                                                      const float* __restrict__ w3,
                                                      const float* __restrict__ w4,
                                                      uint16_t* __restrict__ W32) {
  __shared__ uint16_t Lw[64 * 258];  // [io][yx pad 258], 33 KB
  const int bid = blockIdx.x;
  const int k   = bid >> 8;
  const int io0 = (bid & 255) << 6;
  const float* src = (k == 0) ? w1 : (k == 1) ? w2 : (k == 2) ? w3 : w4;
  const int t = threadIdx.x;
  uint32_t* Lwu = (uint32_t*)Lw;
#pragma unroll
  for (int j = 0; j < 16; ++j) {
    const int idx4 = t + (j << 8);  // 4096 float4s
    const int row  = idx4 >> 6;
    const int c4   = idx4 & 63;
    float4 v = *(const float4*)(src + (((size_t)(io0 + row)) << 8) + (c4 << 2));
    Lwu[row * 129 + (c4 << 1)]     = f2bf(v.x) | (f2bf(v.y) << 16);
    Lwu[row * 129 + (c4 << 1) + 1] = f2bf(v.z) | (f2bf(v.w) << 16);
  }
  __syncthreads();
  const int io_l = t & 63;
  const int pg   = t >> 6;
  uint16_t* dst = W32 + ((size_t)k << 24) + io0 + io_l;
  for (int lp = 0; lp < 256; ++lp) {
    const int p = (lp << 2) + pg;
    const int py = p >> 5, px = p & 31;
    int y0, y1, x0, x1; float fy, fx;
    interp_coord(py, y0, y1, fy);
    interp_coord(px, x0, x1, fx);
    const float c00 = (1.f - fy) * (1.f - fx), c01 = (1.f - fy) * fx;
    const float c10 = fy * (1.f - fx),         c11 = fy * fx;
    const float vA = bf2f(Lw[io_l * 258 + (y0 << 4) + x0]);
    const float vB = bf2f(Lw[io_l * 258 + (y0 << 4) + x1]);
    const float vC = bf2f(Lw[io_l * 258 + (y1 << 4) + x0]);
    const float vD = bf2f(Lw[io_l * 258 + (y1 << 4) + x1]);
    dst[(size_t)p << 14] = (uint16_t)f2bf(c00 * vA + c01 * vB + c10 * vC + c11 * vD);
  }
}

// ---------------------------------------------------------------------------
// Kernel C: per (p,k) 32x128x128 fp32 GEMM.  Stage W32 slice (copy) + A^T,
// inner loop 4x4 per thread, store bf16 ws2[k][p][b][o] fully coalesced.
// ---------------------------------------------------------------------------
__global__ __launch_bounds__(256) void gemm_kernel(const uint16_t* __restrict__ bands,
                                                   const uint16_t* __restrict__ W32,
                                                   uint16_t* __restrict__ ws2) {
  __shared__ uint16_t Ws[16384];   // 32 KB, W slice [i*128+o]
  __shared__ float At[128 * 36];   // 18 KB, A^T [i][b] pad 36
  const int bid = blockIdx.x;
  const int k = bid & 3;
  const int p = bid >> 2;
  const int t = threadIdx.x;
  // stage W slice (straight copy)
  const uint4* wsrc = (const uint4*)(W32 + (((size_t)(k << 10) + p) << 14));
  uint4* wdst = (uint4*)Ws;
#pragma unroll
  for (int j = 0; j < 8; ++j) wdst[t + (j << 8)] = wsrc[t + (j << 8)];
  // stage A^T
  const uint32_t* ab = (const uint32_t*)(bands + (((size_t)(k << 10) + p) << 12));
#pragma unroll
  for (int j = 0; j < 8; ++j) {
    const int idx = t + (j << 8);
    const uint32_t u = ab[idx];
    const int bb = idx >> 6;
    const int i0 = (idx & 63) << 1;
    At[i0 * 36 + bb]       = bf2f(u & 0xffffu);
    At[(i0 + 1) * 36 + bb] = bf2f(u >> 16);
  }
  __syncthreads();
  const int q = t & 31;   // o = 4q+dq
  const int g = t >> 5;   // b = 4g+db
  float acc[16];
#pragma unroll
  for (int j = 0; j < 16; ++j) acc[j] = 0.f;
  const uint32_t* WsuC = (const uint32_t*)Ws;
#pragma unroll 8
  for (int i = 0; i < 128; ++i) {
    float4 av = *(const float4*)&At[i * 36 + (g << 2)];
    uint2 wu  = *(const uint2*)&WsuC[(i << 6) + (q << 1)];
    float w0_ = __uint_as_float(wu.x << 16);
    float w1_ = __uint_as_float(wu.x & 0xffff0000u);
    float w2_ = __uint_as_float(wu.y << 16);
    float w3_ = __uint_as_float(wu.y & 0xffff0000u);
    acc[0]  += av.x * w0_; acc[1]  += av.x * w1_; acc[2]  += av.x * w2_; acc[3]  += av.x * w3_;
    acc[4]  += av.y * w0_; acc[5]  += av.y * w1_; acc[6]  += av.y * w2_; acc[7]  += av.y * w3_;
    acc[8]  += av.z * w0_; acc[9]  += av.z * w1_; acc[10] += av.z * w2_; acc[11] += av.z * w3_;
    acc[12] += av.w * w0_; acc[13] += av.w * w1_; acc[14] += av.w * w2_; acc[15] += av.w * w3_;
  }
  uint32_t* wout = (uint32_t*)(ws2 + (((size_t)(k << 10) + p) << 12));
#pragma unroll
  for (int db = 0; db < 4; ++db) {
    const int b = (g << 2) + db;
    uint32_t u01 = f2bf(acc[db * 4 + 0]) | (f2bf(acc[db * 4 + 1]) << 16);
    uint32_t u23 = f2bf(acc[db * 4 + 2]) | (f2bf(acc[db * 4 + 3]) << 16);
    *(uint2*)&wout[b * 64 + (q << 1)] = make_uint2(u01, u23);
  }
}

// ---------------------------------------------------------------------------
// Kernel D: fused idwt + zero-band 2x upsample.  Block = (b,h): read ws2
// slice coalesced, LDS transpose, write 256 KB of out in 512B runs.
// ---------------------------------------------------------------------------
__global__ __launch_bounds__(256) void idwt_kernel(const uint16_t* __restrict__ ws2,
                                                   float* __restrict__ out) {
  __shared__ uint16_t Ls[4 * 32 * 130];  // [k][w][o pad 130], 33.3 KB
  const int bid = blockIdx.x;
  const int b = bid >> 5;
  const int h = bid & 31;
  const int t = threadIdx.x;
  const uint32_t* su = (const uint32_t*)ws2;
  uint32_t* Lu = (uint32_t*)Ls;
#pragma unroll 4
  for (int j = 0; j < 32; ++j) {
    const int idx = t + (j << 8);   // 0..8191
    const int kw = idx >> 6;        // k*32+w
    const int uo = idx & 63;
    const int k = kw >> 5, w = kw & 31;
    const uint32_t v = su[(((size_t)(k << 10) + (h << 5) + w) << 11) + (b << 6) + uo];
    Lu[kw * 65 + uo] = v;
  }
  __syncthreads();
  const int x4 = t & 31;   // w, and the out float4 index
  const int og = t >> 5;
  for (int pp = 0; pp < 16; ++pp) {
    const int o = (pp << 3) + og;
    const float A = bf2f(Ls[(0 * 32 + x4) * 130 + o]);
    const float B = bf2f(Ls[(1 * 32 + x4) * 130 + o]);
    const float C = bf2f(Ls[(2 * 32 + x4) * 130 + o]);
    const float D = bf2f(Ls[(3 * 32 + x4) * 130 + o]);
    const float E = A + B, F = A - B, G = C + D, Hh = C - D;
    const float vL0 = 0.25f * (E + G),  vR0 = 0.25f * (F + Hh);  // rows 0,1
    const float vL1 = 0.25f * (E - G),  vR1 = 0.25f * (F - Hh);  // rows 2,3
    float* ob = out + (((size_t)(b << 7) + o) << 14) + (h << 9) + (x4 << 2);
    float4 top = make_float4(vL0, vL0, vR0, vR0);
    float4 bot = make_float4(vL1, vL1, vR1, vR1);
    *(float4*)(ob)       = top;
    *(float4*)(ob + 128) = top;
    *(float4*)(ob + 256) = bot;
    *(float4*)(ob + 384) = bot;
  }
}

extern "C" void kernel_launch(void* const* d_in, const int* in_sizes, int n_in,
                              void* d_out, int out_size, void* d_ws, size_t ws_size,
                              hipStream_t stream) {
  const float* x  = (const float*)d_in[0];
  const float* w1 = (const float*)d_in[1];
  const float* w2 = (const float*)d_in[2];
  const float* w3 = (const float*)d_in[3];
  const float* w4 = (const float*)d_in[4];

  uint16_t* bands = (uint16_t*)d_ws;            // 4*1024*4096 bf16 = 33.5 MB
  uint16_t* ws2   = bands + (size_t)16777216;   // 4*1024*4096 bf16 = 33.5 MB
  // W32 (134 MB) lives in d_out as scratch; idwt_kernel rewrites all of d_out
  // afterwards (stream-ordered, no overlap with gemm reads).
  uint16_t* W32 = (uint16_t*)d_out;

  dwt_kernel<<<4096, 256, 0, stream>>>(x, bands);
  winterp_kernel<<<1024, 256, 0, stream>>>(w1, w2, w3, w4, W32);
  gemm_kernel<<<4096, 256, 0, stream>>>(bands, W32, ws2);
  idwt_kernel<<<1024, 256, 0, stream>>>(ws2, (float*)d_out);
}